// Round 1
// baseline (156.059 us; speedup 1.0000x reference)
//
#include <hip/hip_runtime.h>

#define WAVES 8
#define BLOCK (WAVES * 64)

// B=16384, M=41, NMODES=2, HDIM=10, S=419 (read at runtime from in_sizes)
// Layout plan per block: 64 batch elements (lane = batch), 8 waves split the
// S triplet range. E staged in LDS column-major [k][lane] as float4
// (pol0.re, pol0.im, pol1.re, pol1.im) -> one ds_read_b128 per E access.
// All s-indexed weight/index loads made wave-uniform (readfirstlane) -> s_load.

__global__ __launch_bounds__(BLOCK) void eqsonn_kernel(
    const float* __restrict__ x,      // [B,41,2,2]
    const float* __restrict__ task,   // [B,4]
    const float* __restrict__ pbcC,   // [S,2]
    const float* __restrict__ W1,     // [10,2,S,2]
    const float* __restrict__ b1,     // [10,2]
    const float* __restrict__ W2,     // [10,2,41,2]
    const float* __restrict__ b2,     // [10,2]
    const int* __restrict__ m_idx,    // [S]
    const int* __restrict__ n_idx,    // [S]
    float* __restrict__ out,          // [B,2,2]
    int B, int S)
{
    __shared__ float4 Esh[41 * 64];    // 41984 B
    __shared__ float2 D2sh[40 * 64];   // 20480 B (later aliased as acc buffer)

    const int tid  = threadIdx.x;
    const int lane = tid & 63;
    const int wave = tid >> 6;
    const int b0   = blockIdx.x * 64;
    const int b    = b0 + lane;

    // ---- stage E: coalesced float4 global loads -> LDS column-major ----
    for (int e = tid; e < 41 * 64; e += BLOCK) {
        int bb = e / 41;
        int k  = e - bb * 41;
        int bs = b0 + bb; if (bs > B - 1) bs = B - 1;
        float4 v = ((const float4*)x)[(size_t)bs * 41 + k];
        Esh[k * 64 + bb] = v;
    }
    __syncthreads();

    // ---- f2 dots distributed: dot d = (o*2+i)*2+p, wave handles d = wave+8r ----
    {
        float ar[5], ai[5];
#pragma unroll
        for (int r = 0; r < 5; r++) { ar[r] = 0.f; ai[r] = 0.f; }
        int du = __builtin_amdgcn_readfirstlane(wave);
        for (int k = 0; k < 41; k++) {
            float4 E4 = Esh[k * 64 + lane];
#pragma unroll
            for (int r = 0; r < 5; r++) {
                int d = du + 8 * r;
                int o = d >> 2, i = (d >> 1) & 1, p = d & 1;
                float wr = W2[((o * 2 + i) * 41 + k) * 2 + 0];
                float wi = W2[((o * 2 + i) * 41 + k) * 2 + 1];
                float er = p ? E4.z : E4.x;
                float ei = p ? E4.w : E4.y;
                ar[r] += wr * er - wi * ei;
                ai[r] += wr * ei + wi * er;
            }
        }
#pragma unroll
        for (int r = 0; r < 5; r++) {
            int d = du + 8 * r;
            D2sh[d * 64 + lane] = make_float2(ar[r], ai[r]);
        }
    }

    // ---- main triplet loop: this wave's s-chunk ----
    float D[20][4];  // [u=o*2+i][p*2+c]
#pragma unroll
    for (int u = 0; u < 20; u++) { D[u][0] = D[u][1] = D[u][2] = D[u][3] = 0.f; }
    float pbc[4] = {0.f, 0.f, 0.f, 0.f};

    int Q = (S + WAVES - 1) / WAVES;
    int s_begin = wave * Q;
    int s_end   = s_begin + Q; if (s_end > S) s_end = S;
    if (s_begin > S) s_begin = S;
    s_begin = __builtin_amdgcn_readfirstlane(s_begin);
    s_end   = __builtin_amdgcn_readfirstlane(s_end);

    for (int s = s_begin; s < s_end; ++s) {
        int m = m_idx[s];
        int n = n_idx[s];
        float Cr = pbcC[s * 2 + 0], Ci = pbcC[s * 2 + 1];
        float4 Em = Esh[(20 + m) * 64 + lane];
        float4 Eb = Esh[(20 + m + n) * 64 + lane];
        float4 En = Esh[(20 + n) * 64 + lane];
        // sumA = E[c+m,0]*conj(E[c+m+n,0]) + E[c+m,1]*conj(E[c+m+n,1])
        float sr = Em.x * Eb.x + Em.y * Eb.y + Em.z * Eb.z + Em.w * Eb.w;
        float si = Em.y * Eb.x - Em.x * Eb.y + Em.w * Eb.z - Em.z * Eb.w;
        // F_p = sumA * E[c+n,p]
        float F0r = sr * En.x - si * En.y, F0i = sr * En.y + si * En.x;
        float F1r = sr * En.z - si * En.w, F1i = sr * En.w + si * En.z;
        pbc[0] += F0r * Cr - F0i * Ci; pbc[1] += F0r * Ci + F0i * Cr;
        pbc[2] += F1r * Cr - F1i * Ci; pbc[3] += F1r * Ci + F1i * Cr;
#pragma unroll
        for (int u = 0; u < 20; u++) {
            float wr = W1[((size_t)u * S + s) * 2 + 0];
            float wi = W1[((size_t)u * S + s) * 2 + 1];
            D[u][0] += wr * F0r - wi * F0i;
            D[u][1] += wr * F0i + wi * F0r;
            D[u][2] += wr * F1r - wi * F1i;
            D[u][3] += wr * F1i + wi * F1r;
        }
    }
    __syncthreads();  // all f2 D2 writes visible; all waves past their loops

    // ---- Bm from shared D2, partial term (real-linear in partial A) ----
    float t[4] = {0.f, 0.f, 0.f, 0.f};
#pragma unroll
    for (int o = 0; o < 10; o++) {
        float2 d00 = D2sh[((o * 2 + 0) * 2 + 0) * 64 + lane];
        float2 d01 = D2sh[((o * 2 + 0) * 2 + 1) * 64 + lane];
        float2 d10 = D2sh[((o * 2 + 1) * 2 + 0) * 64 + lane];
        float2 d11 = D2sh[((o * 2 + 1) * 2 + 1) * 64 + lane];
        float b2r = b2[o * 2 + 0], b2i = b2[o * 2 + 1];
        float B0r = d00.x + d11.x + b2r, B0i = d00.y + d11.y + b2i;
        float B1r = d01.x + d10.x + b2r, B1i = d01.y + d10.y + b2i;
        float A0r = D[o * 2 + 0][0] + D[o * 2 + 1][2];
        float A0i = D[o * 2 + 0][1] + D[o * 2 + 1][3];
        float A1r = D[o * 2 + 0][2] + D[o * 2 + 1][0];
        float A1i = D[o * 2 + 0][3] + D[o * 2 + 1][1];
        if (wave == 0) {  // b1 contribution exactly once
            float b1r = b1[o * 2 + 0], b1i = b1[o * 2 + 1];
            A0r += b1r; A0i += b1i;
            A1r += b1r; A1i += b1i;
        }
        // A*B*conj(B) + conj(A)*B*B = 2*Re(A*conj(B)) * B
        float g0 = 2.f * (A0r * B0r + A0i * B0i);
        t[0] += g0 * B0r; t[1] += g0 * B0i;
        float g1 = 2.f * (A1r * B1r + A1i * B1i);
        t[2] += g1 * B1r; t[3] += g1 * B1i;
    }

    __syncthreads();  // everyone done reading D2sh; safe to alias as acc
    float4* acc = (float4*)D2sh;  // [WAVES][64][2] float4
    acc[(wave * 64 + lane) * 2 + 0] = make_float4(pbc[0], pbc[1], pbc[2], pbc[3]);
    acc[(wave * 64 + lane) * 2 + 1] = make_float4(t[0], t[1], t[2], t[3]);
    __syncthreads();

    if (wave == 0) {
        float pr0 = 0.f, pi0 = 0.f, pr1 = 0.f, pi1 = 0.f;
        float tr0 = 0.f, ti0 = 0.f, tr1 = 0.f, ti1 = 0.f;
#pragma unroll
        for (int w = 0; w < WAVES; w++) {
            float4 a = acc[(w * 64 + lane) * 2 + 0];
            float4 c = acc[(w * 64 + lane) * 2 + 1];
            pr0 += a.x; pi0 += a.y; pr1 += a.z; pi1 += a.w;
            tr0 += c.x; ti0 += c.y; tr1 += c.z; ti1 += c.w;
        }
        if (b < B) {
            float dbm = task[(size_t)b * 4 + 0];
            // P = 10^(dbm/10)/NMODES = exp2(dbm * log2(10)/10) * 0.5
            float P = exp2f(dbm * 0.33219280948873623f) * 0.5f;
            float kP2 = 3.1622776601683794e-05f * P * P;  // 1e-4/sqrt(10) * P^2
            float4 Ec = Esh[20 * 64 + lane];               // E[c, :]
            float4 o4;
            o4.x = Ec.x + P * pr0 + kP2 * tr0;
            o4.y = Ec.y + P * pi0 + kP2 * ti0;
            o4.z = Ec.z + P * pr1 + kP2 * tr1;
            o4.w = Ec.w + P * pi1 + kP2 * ti1;
            ((float4*)out)[b] = o4;
        }
    }
}

extern "C" void kernel_launch(void* const* d_in, const int* in_sizes, int n_in,
                              void* d_out, int out_size, void* d_ws, size_t ws_size,
                              hipStream_t stream) {
    const float* x     = (const float*)d_in[0];
    const float* task  = (const float*)d_in[1];
    const float* pbcC  = (const float*)d_in[2];
    const float* W1    = (const float*)d_in[3];
    const float* b1    = (const float*)d_in[4];
    const float* W2    = (const float*)d_in[5];
    const float* b2    = (const float*)d_in[6];
    const int*   m_idx = (const int*)d_in[7];
    const int*   n_idx = (const int*)d_in[8];
    float* out = (float*)d_out;

    int S = in_sizes[7];             // m_idx element count
    int B = in_sizes[0] / (41 * 2 * 2);

    int grid = (B + 63) / 64;
    eqsonn_kernel<<<grid, BLOCK, 0, stream>>>(x, task, pbcC, W1, b1, W2, b2,
                                              m_idx, n_idx, out, B, S);
}

// Round 2
// 140.440 us; speedup vs baseline: 1.1112x; 1.1112x over previous
//
#include <hip/hip_runtime.h>

#define WAVES 16
#define BLOCK (WAVES * 64)

// B=16384, M=41, NMODES=2, HDIM=10, S=419 (runtime from in_sizes)
// lane = batch element (64/block), 16 waves split the S range (~27 s each).
// Accumulators held in the reduced basis A[o][p] = D[o,0,p]+D[o,1,1-p]
// (40 floats/wave, fits VGPRs -> no AGPR round-trips).
// E staged in LDS column-major [k][lane] as float4 -> ds_read_b128.
// All s-indexed loads wave-uniform -> s_load.

__global__ __launch_bounds__(BLOCK, 4) void eqsonn_kernel(
    const float* __restrict__ x,      // [B,41,2,2]
    const float* __restrict__ task,   // [B,4]
    const float* __restrict__ pbcC,   // [S,2]
    const float* __restrict__ W1,     // [10,2,S,2]
    const float* __restrict__ b1,     // [10,2]
    const float* __restrict__ W2,     // [10,2,41,2]
    const float* __restrict__ b2,     // [10,2]
    const int* __restrict__ m_idx,    // [S]
    const int* __restrict__ n_idx,    // [S]
    float* __restrict__ out,          // [B,2,2]
    int B, int S)
{
    __shared__ float4 Esh[41 * 64];    // 41984 B
    __shared__ float2 D2sh[40 * 64];   // 20480 B (f2 dots; later aliased as acc)

    const int tid  = threadIdx.x;
    const int lane = tid & 63;
    const int wave = tid >> 6;
    const int b0   = blockIdx.x * 64;
    const int b    = b0 + lane;

    // ---- stage E: coalesced float4 global loads -> LDS column-major ----
    for (int e = tid; e < 41 * 64; e += BLOCK) {
        int bb = e / 41;
        int k  = e - bb * 41;
        int bs = b0 + bb; if (bs > B - 1) bs = B - 1;
        Esh[k * 64 + bb] = ((const float4*)x)[(size_t)bs * 41 + k];
    }
    __syncthreads();

    // ---- f2 dots: d = (o*2+i)*2+p ; wave handles d = wave + 16r ----
    {
        float ar[3] = {0.f, 0.f, 0.f}, ai[3] = {0.f, 0.f, 0.f};
        int du = __builtin_amdgcn_readfirstlane(wave);
        for (int k = 0; k < 41; k++) {
            float4 E4 = Esh[k * 64 + lane];
#pragma unroll
            for (int r = 0; r < 3; r++) {
                int d = du + 16 * r;
                if (d < 40) {
                    int o = d >> 2, i = (d >> 1) & 1, p = d & 1;
                    float wr = W2[((o * 2 + i) * 41 + k) * 2 + 0];
                    float wi = W2[((o * 2 + i) * 41 + k) * 2 + 1];
                    float er = p ? E4.z : E4.x;
                    float ei = p ? E4.w : E4.y;
                    ar[r] += wr * er - wi * ei;
                    ai[r] += wr * ei + wi * er;
                }
            }
        }
#pragma unroll
        for (int r = 0; r < 3; r++) {
            int d = du + 16 * r;
            if (d < 40) D2sh[d * 64 + lane] = make_float2(ar[r], ai[r]);
        }
    }

    // ---- main triplet loop: this wave's s-chunk, reduced-basis accumulators ----
    float A[10][4];  // [o][{A0r,A0i,A1r,A1i}]
#pragma unroll
    for (int o = 0; o < 10; o++) { A[o][0] = A[o][1] = A[o][2] = A[o][3] = 0.f; }
    float pbc[4] = {0.f, 0.f, 0.f, 0.f};

    int Q = (S + WAVES - 1) / WAVES;
    int s_begin = wave * Q;
    int s_end   = s_begin + Q;
    if (s_end > S) s_end = S;
    if (s_begin > S) s_begin = S;
    s_begin = __builtin_amdgcn_readfirstlane(s_begin);
    s_end   = __builtin_amdgcn_readfirstlane(s_end);

    for (int s = s_begin; s < s_end; ++s) {
        int m = m_idx[s];
        int n = n_idx[s];
        float Cr = pbcC[s * 2 + 0], Ci = pbcC[s * 2 + 1];
        float4 Em = Esh[(20 + m) * 64 + lane];
        float4 Eb = Esh[(20 + m + n) * 64 + lane];
        float4 En = Esh[(20 + n) * 64 + lane];
        // sumA = E[c+m,0]*conj(E[c+m+n,0]) + E[c+m,1]*conj(E[c+m+n,1])
        float sr = Em.x * Eb.x + Em.y * Eb.y + Em.z * Eb.z + Em.w * Eb.w;
        float si = Em.y * Eb.x - Em.x * Eb.y + Em.w * Eb.z - Em.z * Eb.w;
        // F_p = sumA * E[c+n,p]
        float F0r = sr * En.x - si * En.y, F0i = sr * En.y + si * En.x;
        float F1r = sr * En.z - si * En.w, F1i = sr * En.w + si * En.z;
        pbc[0] += F0r * Cr - F0i * Ci; pbc[1] += F0r * Ci + F0i * Cr;
        pbc[2] += F1r * Cr - F1i * Ci; pbc[3] += F1r * Ci + F1i * Cr;
#pragma unroll
        for (int o = 0; o < 10; o++) {
            float w0r = W1[((size_t)(o * 2 + 0) * S + s) * 2 + 0];
            float w0i = W1[((size_t)(o * 2 + 0) * S + s) * 2 + 1];
            float w1r = W1[((size_t)(o * 2 + 1) * S + s) * 2 + 0];
            float w1i = W1[((size_t)(o * 2 + 1) * S + s) * 2 + 1];
            A[o][0] += w0r * F0r - w0i * F0i + w1r * F1r - w1i * F1i;
            A[o][1] += w0r * F0i + w0i * F0r + w1r * F1i + w1i * F1r;
            A[o][2] += w0r * F1r - w0i * F1i + w1r * F0r - w1i * F0i;
            A[o][3] += w0r * F1i + w0i * F1r + w1r * F0i + w1i * F0r;
        }
    }
    __syncthreads();  // f2 D2 writes visible; all waves past their loops

    // ---- Bm from shared D2, partial term (real-linear in partial A) ----
    float t[4] = {0.f, 0.f, 0.f, 0.f};
#pragma unroll
    for (int o = 0; o < 10; o++) {
        float2 d00 = D2sh[((o * 2 + 0) * 2 + 0) * 64 + lane];
        float2 d01 = D2sh[((o * 2 + 0) * 2 + 1) * 64 + lane];
        float2 d10 = D2sh[((o * 2 + 1) * 2 + 0) * 64 + lane];
        float2 d11 = D2sh[((o * 2 + 1) * 2 + 1) * 64 + lane];
        float b2r = b2[o * 2 + 0], b2i = b2[o * 2 + 1];
        float B0r = d00.x + d11.x + b2r, B0i = d00.y + d11.y + b2i;
        float B1r = d01.x + d10.x + b2r, B1i = d01.y + d10.y + b2i;
        float A0r = A[o][0], A0i = A[o][1];
        float A1r = A[o][2], A1i = A[o][3];
        if (wave == 0) {  // b1 contribution exactly once
            float b1r = b1[o * 2 + 0], b1i = b1[o * 2 + 1];
            A0r += b1r; A0i += b1i;
            A1r += b1r; A1i += b1i;
        }
        // A*B*conj(B) + conj(A)*B*B = 2*Re(A*conj(B)) * B
        float g0 = 2.f * (A0r * B0r + A0i * B0i);
        t[0] += g0 * B0r; t[1] += g0 * B0i;
        float g1 = 2.f * (A1r * B1r + A1i * B1i);
        t[2] += g1 * B1r; t[3] += g1 * B1i;
    }

    // ---- fold P / kP^2 per wave, single float4 partial per (wave,lane) ----
    int bt = (b < B) ? b : (B - 1);
    float dbm = task[(size_t)bt * 4 + 0];
    float P   = exp2f(dbm * 0.33219280948873623f) * 0.5f;   // 10^(dbm/10)/2
    float kP2 = 3.1622776601683794e-05f * P * P;            // 1e-4/sqrt(10)*P^2
    float4 contrib;
    contrib.x = P * pbc[0] + kP2 * t[0];
    contrib.y = P * pbc[1] + kP2 * t[1];
    contrib.z = P * pbc[2] + kP2 * t[2];
    contrib.w = P * pbc[3] + kP2 * t[3];

    __syncthreads();  // everyone done reading D2sh; safe to alias
    float4* acc = (float4*)D2sh;  // [WAVES][64] float4 = 16 KB
    acc[wave * 64 + lane] = contrib;
    __syncthreads();

    if (wave == 0) {
        float4 sum = acc[lane];
#pragma unroll
        for (int w = 1; w < WAVES; w++) {
            float4 c = acc[w * 64 + lane];
            sum.x += c.x; sum.y += c.y; sum.z += c.z; sum.w += c.w;
        }
        if (b < B) {
            float4 Ec = Esh[20 * 64 + lane];  // E[c, :]
            float4 o4;
            o4.x = Ec.x + sum.x;
            o4.y = Ec.y + sum.y;
            o4.z = Ec.z + sum.z;
            o4.w = Ec.w + sum.w;
            ((float4*)out)[b] = o4;
        }
    }
}

extern "C" void kernel_launch(void* const* d_in, const int* in_sizes, int n_in,
                              void* d_out, int out_size, void* d_ws, size_t ws_size,
                              hipStream_t stream) {
    const float* x     = (const float*)d_in[0];
    const float* task  = (const float*)d_in[1];
    const float* pbcC  = (const float*)d_in[2];
    const float* W1    = (const float*)d_in[3];
    const float* b1    = (const float*)d_in[4];
    const float* W2    = (const float*)d_in[5];
    const float* b2    = (const float*)d_in[6];
    const int*   m_idx = (const int*)d_in[7];
    const int*   n_idx = (const int*)d_in[8];
    float* out = (float*)d_out;

    int S = in_sizes[7];             // m_idx element count
    int B = in_sizes[0] / (41 * 2 * 2);

    int grid = (B + 63) / 64;
    eqsonn_kernel<<<grid, BLOCK, 0, stream>>>(x, task, pbcC, W1, b1, W2, b2,
                                              m_idx, n_idx, out, B, S);
}